// Round 3
// baseline (327.686 us; speedup 1.0000x reference)
//
#include <hip/hip_runtime.h>
#include <hip/hip_bf16.h>

#define B_SZ 512
#define I_SZ 7
#define D_SZ 512
#define J_SZ 64
#define E_SZ 128
#define N_SZ 8192
#define ITERS 10

typedef __attribute__((ext_vector_type(8))) short bf16x8;
typedef __attribute__((ext_vector_type(4))) float f32x4;

#if defined(__has_builtin)
#if __has_builtin(__builtin_amdgcn_cvt_pk_bf16_f32)
#define HAVE_CVT_PK_BF16 1
#endif
#endif

// Split a PAIR of fp32 into packed-bf16 hi and lo words (RNE both stages).
// hp low short = bf16(x0), high short = bf16(x1); same for lp with residuals.
__device__ inline void split2(float x0, float x1, unsigned& hp, unsigned& lp) {
#ifdef HAVE_CVT_PK_BF16
    auto h = __builtin_amdgcn_cvt_pk_bf16_f32(x0, x1);
    hp = __builtin_bit_cast(unsigned, h);
    union { unsigned u; float f; } b0, b1;
    b0.u = hp << 16;
    b1.u = hp & 0xFFFF0000u;
    auto l = __builtin_amdgcn_cvt_pk_bf16_f32(x0 - b0.f, x1 - b1.f);
    lp = __builtin_bit_cast(unsigned, l);
#else
    union { float f; unsigned u; } u0, u1;
    u0.f = x0; u1.f = x1;
    unsigned r0 = u0.u + 0x7FFF + ((u0.u >> 16) & 1);
    unsigned r1 = u1.u + 0x7FFF + ((u1.u >> 16) & 1);
    hp = __builtin_amdgcn_perm(r1, r0, 0x07060302);   // [r1.hi16 | r0.hi16]
    union { unsigned u; float f; } h0, h1;
    h0.u = r0 & 0xFFFF0000u;
    h1.u = r1 & 0xFFFF0000u;
    union { float f; unsigned u; } s0, s1;
    s0.f = x0 - h0.f; s1.f = x1 - h1.f;
    unsigned q0 = s0.u + 0x7FFF + ((s0.u >> 16) & 1);
    unsigned q1 = s1.u + 0x7FFF + ((s1.u >> 16) & 1);
    lp = __builtin_amdgcn_perm(q1, q0, 0x07060302);
#endif
}

// ---------------------------------------------------------------------------
// Kernel 1 (R8): vote GEMM, 128x128 tile, BK=32, 256 threads (4 waves x 64x64).
// fW[b,i,j,e] = sum_d f[b,i,d]*W[i,d,j,e].  Per i: C[512,8192]=A[512,512]*B.
// R7 pipeline kept (split-at-staging, T14 issue-early/write-late, dbuf,
// ONE barrier/tile, setprio), with two fixes from the R7 post-mortem:
//   (a) 2 blocks/CU co-residency: LDS = 2 slots x 32 KiB = 64 KiB. Independent
//       blocks have independent barriers -> stalls of one block are filled by
//       the other (R5's 134us at 2.25 blocks proved this is the overlap lever).
//   (b) correct b128 swizzle: granule(row,chunk) = 4*row + chunk (mod 8), so
//       pos = chunk ^ ((row>>1)&3)  (R7 used row bits 0..1 -> odd/even rows
//       collided -> 5.5e6 conflicts).  Verified: staging writes (4 rows x 2 kh
//       per 8-lane group) and frag reads (8 rows per group) tile all 8
//       granules -> conflict-free at the b128 floor.
// acc += Ahi*Bhi + Ahi*Blo + Alo*Bhi  (lo*lo dropped, same math as R5-R7).
// ---------------------------------------------------------------------------
__global__ __launch_bounds__(256, 2) void vote_gemm_mfma(
    const float* __restrict__ f,   // [B, I, D]
    const float* __restrict__ W,   // [I, D, N]
    float* __restrict__ fW)        // [B, I, N]
{
    const int i  = blockIdx.z;
    const int m0 = blockIdx.y * 128;
    const int n0 = blockIdx.x * 128;
    const int th = threadIdx.x;
    const int lane = th & 63;
    const int wave = th >> 6;
    const int wr   = wave >> 1;    // 0..1: 64-row half
    const int wc   = wave & 1;     // 0..1: 64-col half
    const int quad = lane >> 4;    // 0..3: k-chunk of the fragment
    const int lm   = lane & 15;

    __shared__ short Ah_s[2][128 * 32];
    __shared__ short Al_s[2][128 * 32];
    __shared__ short Bh_s[2][128 * 32];
    __shared__ short Bl_s[2][128 * 32];

    // ---- staging map: thread -> (row sm, k-half kh); same for A and B ----
    const int sm = th >> 1;        // A row m / B col n, 0..127
    const int kh = th & 1;         // 16-k half
    const int swz = (sm >> 1) & 3; // b128 granule swizzle (row bits 1..2)
    const int wo0 = sm * 32 + (((kh << 1) | 0) ^ swz) * 8;   // chunk 2kh
    const int wo1 = sm * 32 + (((kh << 1) | 1) ^ swz) * 8;   // chunk 2kh+1

    const float* aPtr = f + (size_t)(m0 + sm) * (I_SZ * D_SZ) + (size_t)i * D_SZ + kh * 16;
    const float* bPtr = W + (size_t)i * D_SZ * N_SZ + (size_t)(kh * 16) * N_SZ + n0 + sm;

    // ---- fragment read chunk position (same swizzle; row bits 1..2 = lm>>1) ----
    const int fpos8 = (quad ^ ((lm >> 1) & 3)) * 8;

    f32x4 acc[4][4];
#pragma unroll
    for (int a = 0; a < 4; ++a)
#pragma unroll
        for (int c = 0; c < 4; ++c)
            acc[a][c] = (f32x4){0.f, 0.f, 0.f, 0.f};

    float av[16], bv[16];
    auto stage_load = [&](int kt) {
        const float* pa = aPtr + kt * 32;
        float4 t0 = *(const float4*)(pa);
        float4 t1 = *(const float4*)(pa + 4);
        float4 t2 = *(const float4*)(pa + 8);
        float4 t3 = *(const float4*)(pa + 12);
        av[0]=t0.x;  av[1]=t0.y;  av[2]=t0.z;  av[3]=t0.w;
        av[4]=t1.x;  av[5]=t1.y;  av[6]=t1.z;  av[7]=t1.w;
        av[8]=t2.x;  av[9]=t2.y;  av[10]=t2.z; av[11]=t2.w;
        av[12]=t3.x; av[13]=t3.y; av[14]=t3.z; av[15]=t3.w;
        const float* pb = bPtr + (size_t)kt * 32 * N_SZ;
#pragma unroll
        for (int r = 0; r < 16; ++r) bv[r] = pb[(size_t)r * N_SZ];
    };
    auto stage_write = [&](int slot) {
        short* qAh = &Ah_s[slot][0]; short* qAl = &Al_s[slot][0];
        short* qBh = &Bh_s[slot][0]; short* qBl = &Bl_s[slot][0];
        uint4 h, l;
        split2(av[0],  av[1],  h.x, l.x); split2(av[2],  av[3],  h.y, l.y);
        split2(av[4],  av[5],  h.z, l.z); split2(av[6],  av[7],  h.w, l.w);
        *(uint4*)&qAh[wo0] = h; *(uint4*)&qAl[wo0] = l;
        split2(av[8],  av[9],  h.x, l.x); split2(av[10], av[11], h.y, l.y);
        split2(av[12], av[13], h.z, l.z); split2(av[14], av[15], h.w, l.w);
        *(uint4*)&qAh[wo1] = h; *(uint4*)&qAl[wo1] = l;
        split2(bv[0],  bv[1],  h.x, l.x); split2(bv[2],  bv[3],  h.y, l.y);
        split2(bv[4],  bv[5],  h.z, l.z); split2(bv[6],  bv[7],  h.w, l.w);
        *(uint4*)&qBh[wo0] = h; *(uint4*)&qBl[wo0] = l;
        split2(bv[8],  bv[9],  h.x, l.x); split2(bv[10], bv[11], h.y, l.y);
        split2(bv[12], bv[13], h.z, l.z); split2(bv[14], bv[15], h.w, l.w);
        *(uint4*)&qBh[wo1] = h; *(uint4*)&qBl[wo1] = l;
    };

    // ---- prologue: stage tile 0 synchronously into slot 0 ----
    stage_load(0);
    stage_write(0);
    __syncthreads();

    for (int t = 0; t < 16; ++t) {
        const int s = t & 1;
        const short* pAh = &Ah_s[s][0]; const short* pAl = &Al_s[s][0];
        const short* pBh = &Bh_s[s][0]; const short* pBl = &Bl_s[s][0];

        // ---- 1. issue next-tile global loads (consumed at step 3) ----
        if (t < 15) stage_load(t + 1);
        __builtin_amdgcn_sched_barrier(0);

        // ---- 2. B fragments (held across the tile) + ms 0..2 ----
        bf16x8 Bf_h[4], Bf_l[4];
#pragma unroll
        for (int ns = 0; ns < 4; ++ns) {
            const int o = (wc * 64 + ns * 16 + lm) * 32 + fpos8;
            Bf_h[ns] = *(const bf16x8*)&pBh[o];
            Bf_l[ns] = *(const bf16x8*)&pBl[o];
        }
#pragma unroll
        for (int ms = 0; ms < 3; ++ms) {
            const int o = (wr * 64 + ms * 16 + lm) * 32 + fpos8;
            const bf16x8 Af_h = *(const bf16x8*)&pAh[o];
            const bf16x8 Af_l = *(const bf16x8*)&pAl[o];
            __builtin_amdgcn_s_setprio(1);
#pragma unroll
            for (int ns = 0; ns < 4; ++ns) {
                acc[ms][ns] = __builtin_amdgcn_mfma_f32_16x16x32_bf16(Af_h, Bf_h[ns], acc[ms][ns], 0, 0, 0);
                acc[ms][ns] = __builtin_amdgcn_mfma_f32_16x16x32_bf16(Af_h, Bf_l[ns], acc[ms][ns], 0, 0, 0);
                acc[ms][ns] = __builtin_amdgcn_mfma_f32_16x16x32_bf16(Af_l, Bf_h[ns], acc[ms][ns], 0, 0, 0);
            }
            __builtin_amdgcn_s_setprio(0);
        }
        __builtin_amdgcn_sched_barrier(0);

        // ---- 3. split + write tile t+1 into the other slot ----
        if (t < 15) stage_write(s ^ 1);
        __builtin_amdgcn_sched_barrier(0);

        // ---- 4. ms 3 ----
        {
            const int o = (wr * 64 + 3 * 16 + lm) * 32 + fpos8;
            const bf16x8 Af_h = *(const bf16x8*)&pAh[o];
            const bf16x8 Af_l = *(const bf16x8*)&pAl[o];
            __builtin_amdgcn_s_setprio(1);
#pragma unroll
            for (int ns = 0; ns < 4; ++ns) {
                acc[3][ns] = __builtin_amdgcn_mfma_f32_16x16x32_bf16(Af_h, Bf_h[ns], acc[3][ns], 0, 0, 0);
                acc[3][ns] = __builtin_amdgcn_mfma_f32_16x16x32_bf16(Af_h, Bf_l[ns], acc[3][ns], 0, 0, 0);
                acc[3][ns] = __builtin_amdgcn_mfma_f32_16x16x32_bf16(Af_l, Bf_h[ns], acc[3][ns], 0, 0, 0);
            }
            __builtin_amdgcn_s_setprio(0);
        }
        __builtin_amdgcn_sched_barrier(0);

        // ---- 5. one barrier per tile: writes visible, slot swap ----
        __syncthreads();
    }

    // ---- write C: D layout col=lane&15, row=quad*4+reg (verified R5-R7) ----
#pragma unroll
    for (int ms = 0; ms < 4; ++ms) {
        const int rowb = m0 + wr * 64 + ms * 16 + quad * 4;
#pragma unroll
        for (int ns = 0; ns < 4; ++ns) {
            const int col = n0 + wc * 64 + ns * 16 + lm;
#pragma unroll
            for (int r = 0; r < 4; ++r)
                fW[((size_t)(rowb + r) * I_SZ + i) * N_SZ + col] = acc[ms][ns][r];
        }
    }
}

// ---------------------------------------------------------------------------
// Kernel 2: routing via Gram matrices (unchanged).
// ---------------------------------------------------------------------------
__global__ __launch_bounds__(1024) void routing_kernel(
    const float* __restrict__ fW,  // [B, I, N]
    const float* __restrict__ p,   // [B, I]
    float* __restrict__ c_out,     // [B, J, E]
    float* __restrict__ r_out)     // [B, I, J]
{
    const int b   = blockIdx.x;
    const int tid = threadIdx.x;
    const int j   = tid >> 4;      // 0..63
    const int sub = tid & 15;      // e-chunk [sub*8, sub*8+8)

    __shared__ float G_sh[64][49];
    __shared__ float s_sh[64][9];
    __shared__ float w_sh[2][64][9];
    __shared__ float p_sh[8];

    if (tid < I_SZ) p_sh[tid] = p[(size_t)b * I_SZ + tid];

    float4 fw[I_SZ][2];
    const float* base = fW + (size_t)b * I_SZ * N_SZ + j * E_SZ + sub * 8;
#pragma unroll
    for (int i = 0; i < I_SZ; ++i) {
        fw[i][0] = *(const float4*)(base + (size_t)i * N_SZ);
        fw[i][1] = *(const float4*)(base + (size_t)i * N_SZ + 4);
    }

    // ---- Phase 1: Gram + row sums (reduce over 16 sub-lanes) ----
#pragma unroll
    for (int i = 0; i < I_SZ; ++i) {
        float s = fw[i][0].x + fw[i][0].y + fw[i][0].z + fw[i][0].w
                + fw[i][1].x + fw[i][1].y + fw[i][1].z + fw[i][1].w;
        s += __shfl_xor(s, 1); s += __shfl_xor(s, 2);
        s += __shfl_xor(s, 4); s += __shfl_xor(s, 8);
        if (sub == 0) s_sh[j][i] = s;
#pragma unroll
        for (int i2 = i; i2 < I_SZ; ++i2) {
            float g = fw[i][0].x * fw[i2][0].x + fw[i][0].y * fw[i2][0].y
                    + fw[i][0].z * fw[i2][0].z + fw[i][0].w * fw[i2][0].w
                    + fw[i][1].x * fw[i2][1].x + fw[i][1].y * fw[i2][1].y
                    + fw[i][1].z * fw[i2][1].z + fw[i][1].w * fw[i2][1].w;
            g += __shfl_xor(g, 1); g += __shfl_xor(g, 2);
            g += __shfl_xor(g, 4); g += __shfl_xor(g, 8);
            if (sub == 0) { G_sh[j][i * 7 + i2] = g; G_sh[j][i2 * 7 + i] = g; }
        }
    }
    __syncthreads();

    // ---- Phase 2: 10 iterations on the 7x7 system ----
    for (int t = 0; t < ITERS; ++t) {
        if (tid < I_SZ * 64) {                 // waves 0..6
            const int ii = tid >> 6;
            const int jj = tid & 63;
            float l;
            if (t == 0) {
                l = s_sh[jj][ii];              // c0 = ones
            } else {
                const int rb = t & 1;
                l = 0.f;
#pragma unroll
                for (int i2 = 0; i2 < I_SZ; ++i2)
                    l = fmaf(w_sh[rb][jj][i2], G_sh[jj][ii * 7 + i2], l);
            }
            float mx = l;
#pragma unroll
            for (int off = 32; off > 0; off >>= 1)
                mx = fmaxf(mx, __shfl_xor(mx, off));
            float ex = __expf(l - mx);
            float sm = ex;
#pragma unroll
            for (int off = 32; off > 0; off >>= 1)
                sm += __shfl_xor(sm, off);
            float r = ex / sm;
            if (t == ITERS - 1)
                r_out[(size_t)b * (I_SZ * J_SZ) + ii * 64 + jj] = r;
            w_sh[(t + 1) & 1][jj][ii] = p_sh[ii] * r;
        }
        __syncthreads();
    }

    // ---- Phase 3: c from registers ----
    float4 a0 = make_float4(0.f, 0.f, 0.f, 0.f);
    float4 a1 = make_float4(0.f, 0.f, 0.f, 0.f);
#pragma unroll
    for (int i = 0; i < I_SZ; ++i) {
        float wv = w_sh[ITERS & 1][j][i];
        a0.x = fmaf(wv, fw[i][0].x, a0.x); a0.y = fmaf(wv, fw[i][0].y, a0.y);
        a0.z = fmaf(wv, fw[i][0].z, a0.z); a0.w = fmaf(wv, fw[i][0].w, a0.w);
        a1.x = fmaf(wv, fw[i][1].x, a1.x); a1.y = fmaf(wv, fw[i][1].y, a1.y);
        a1.z = fmaf(wv, fw[i][1].z, a1.z); a1.w = fmaf(wv, fw[i][1].w, a1.w);
    }
    float* dst = c_out + (size_t)b * N_SZ + j * E_SZ + sub * 8;
    *(float4*)(dst)     = a0;
    *(float4*)(dst + 4) = a1;
}

extern "C" void kernel_launch(void* const* d_in, const int* in_sizes, int n_in,
                              void* d_out, int out_size, void* d_ws, size_t ws_size,
                              hipStream_t stream) {
    const float* f = (const float*)d_in[0];   // [512,7,512]
    const float* p = (const float*)d_in[1];   // [512,7]
    const float* W = (const float*)d_in[2];   // [7,512,64,128]
    float* out = (float*)d_out;               // c (512*64*128) then r (512*7*64)
    float* fW  = (float*)d_ws;                // 117.4 MB scratch

    vote_gemm_mfma<<<dim3(N_SZ / 128, B_SZ / 128, I_SZ), 256, 0, stream>>>(f, W, fW);
    routing_kernel<<<B_SZ, 1024, 0, stream>>>(fW, p, out, out + (size_t)B_SZ * N_SZ);
}

// Round 4
// 323.820 us; speedup vs baseline: 1.0119x; 1.0119x over previous
//
#include <hip/hip_runtime.h>
#include <hip/hip_bf16.h>

#define B_SZ 512
#define I_SZ 7
#define D_SZ 512
#define J_SZ 64
#define E_SZ 128
#define N_SZ 8192
#define ITERS 10

typedef __attribute__((ext_vector_type(8))) short bf16x8;
typedef __attribute__((ext_vector_type(4))) float f32x4;

#if defined(__has_builtin)
#if __has_builtin(__builtin_amdgcn_cvt_pk_bf16_f32)
#define HAVE_CVT_PK_BF16 1
#endif
#endif

// Split a PAIR of fp32 into packed-bf16 hi and lo words (RNE both stages).
// hp low short = bf16(x0), high short = bf16(x1); same for lp with residuals.
__device__ inline void split2(float x0, float x1, unsigned& hp, unsigned& lp) {
#ifdef HAVE_CVT_PK_BF16
    auto h = __builtin_amdgcn_cvt_pk_bf16_f32(x0, x1);
    hp = __builtin_bit_cast(unsigned, h);
    union { unsigned u; float f; } b0, b1;
    b0.u = hp << 16;
    b1.u = hp & 0xFFFF0000u;
    auto l = __builtin_amdgcn_cvt_pk_bf16_f32(x0 - b0.f, x1 - b1.f);
    lp = __builtin_bit_cast(unsigned, l);
#else
    union { float f; unsigned u; } u0, u1;
    u0.f = x0; u1.f = x1;
    unsigned r0 = u0.u + 0x7FFF + ((u0.u >> 16) & 1);
    unsigned r1 = u1.u + 0x7FFF + ((u1.u >> 16) & 1);
    hp = __builtin_amdgcn_perm(r1, r0, 0x07060302);   // [r1.hi16 | r0.hi16]
    union { unsigned u; float f; } h0, h1;
    h0.u = r0 & 0xFFFF0000u;
    h1.u = r1 & 0xFFFF0000u;
    union { float f; unsigned u; } s0, s1;
    s0.f = x0 - h0.f; s1.f = x1 - h1.f;
    unsigned q0 = s0.u + 0x7FFF + ((s0.u >> 16) & 1);
    unsigned q1 = s1.u + 0x7FFF + ((s1.u >> 16) & 1);
    lp = __builtin_amdgcn_perm(q1, q0, 0x07060302);
#endif
}

// ---------------------------------------------------------------------------
// Kernel 1 (R9): vote GEMM, 256x256 tile, BK=32, 512 threads (8 waves x 128x64).
// fW[b,i,j,e] = sum_d f[b,i,d]*W[i,d,j,e].  Per i: C[512,8192]=A[512,512]*B.
// Synthesis of what measured well:
//  - 256^2 tile (R7): staging cost per thread is FIXED (32 floats), MFMA/wave
//    scales with wave-tile -> 96 MFMA vs ~96 split-VALU = 2.4:1 (128^2 was 1:1).
//  - R8's swizzle, hardware-validated 0 conflicts: chunk pos = c ^ ((row>>1)&3)
//    on [row][32-short] rows (b128 granule = (4*row + pos) mod 8).
//  - FULL-TILE prefetch distance: global loads for t+1 issued at tile-t top,
//    split+ds_write at tile-t end -> ~3700 cy of MFMA cover the W-load latency
//    (R8 exposed it after only ~300 cy -> per-tile stall).
//  - m201-style phases: 4 per K-tile, each {4 A-frag b128 reads -> setprio(1)
//    -> 24 MFMA -> setprio(0) -> s_barrier}; B frags read once in ph0.
//    Barrier-locked waves overlap one wave's LDS burst with others' MFMA.
// Pipe budget/CU/K-tile: MFMA 3725 cy > LDS 3072 > VALU 544/SIMD -> MFMA-bound.
// acc += Ahi*Bhi + Ahi*Blo + Alo*Bhi  (lo*lo dropped, same math as R5-R8).
// ---------------------------------------------------------------------------
__global__ __launch_bounds__(512, 2) void vote_gemm_mfma(
    const float* __restrict__ f,   // [B, I, D]
    const float* __restrict__ W,   // [I, D, N]
    float* __restrict__ fW)        // [B, I, N]
{
    const int i  = blockIdx.z;
    const int m0 = blockIdx.y * 256;
    const int n0 = blockIdx.x * 256;
    const int th = threadIdx.x;
    const int lane = th & 63;
    const int wave = th >> 6;
    const int wr   = wave >> 2;    // 0..1: 128-row half
    const int wc   = wave & 3;     // 0..3: 64-col quarter
    const int quad = lane >> 4;    // 0..3: k-chunk of the fragment
    const int lm   = lane & 15;

    __shared__ short Ah_s[2][256 * 32];   // 16 KiB per slot-plane
    __shared__ short Al_s[2][256 * 32];
    __shared__ short Bh_s[2][256 * 32];
    __shared__ short Bl_s[2][256 * 32];   // total 128 KiB

    // ---- staging map: thread -> (row sm, k-half kh); same for A and B ----
    const int sm = th >> 1;        // A row m / B col n, 0..255
    const int kh = th & 1;         // 16-k half
    const int swz = (sm >> 1) & 3; // b128 granule swizzle (row bits 1..2) [R8-validated]
    const int wo0 = sm * 32 + (((kh << 1) | 0) ^ swz) * 8;   // chunk 2kh
    const int wo1 = sm * 32 + (((kh << 1) | 1) ^ swz) * 8;   // chunk 2kh+1

    const float* aPtr = f + (size_t)(m0 + sm) * (I_SZ * D_SZ) + (size_t)i * D_SZ + kh * 16;
    const float* bPtr = W + (size_t)i * D_SZ * N_SZ + (size_t)(kh * 16) * N_SZ + n0 + sm;

    // ---- fragment read chunk position (same swizzle; row bits 1..2 = lm>>1) ----
    const int fpos8 = (quad ^ ((lm >> 1) & 3)) * 8;

    f32x4 acc[8][4];
#pragma unroll
    for (int a = 0; a < 8; ++a)
#pragma unroll
        for (int c = 0; c < 4; ++c)
            acc[a][c] = (f32x4){0.f, 0.f, 0.f, 0.f};

    float av[16], bv[16];
    auto stage_load = [&](int kt) {
        const float* pa = aPtr + kt * 32;
        float4 t0 = *(const float4*)(pa);
        float4 t1 = *(const float4*)(pa + 4);
        float4 t2 = *(const float4*)(pa + 8);
        float4 t3 = *(const float4*)(pa + 12);
        av[0]=t0.x;  av[1]=t0.y;  av[2]=t0.z;  av[3]=t0.w;
        av[4]=t1.x;  av[5]=t1.y;  av[6]=t1.z;  av[7]=t1.w;
        av[8]=t2.x;  av[9]=t2.y;  av[10]=t2.z; av[11]=t2.w;
        av[12]=t3.x; av[13]=t3.y; av[14]=t3.z; av[15]=t3.w;
        const float* pb = bPtr + (size_t)kt * 32 * N_SZ;
#pragma unroll
        for (int r = 0; r < 16; ++r) bv[r] = pb[(size_t)r * N_SZ];
    };
    auto stage_write = [&](int slot) {
        short* qAh = &Ah_s[slot][0]; short* qAl = &Al_s[slot][0];
        short* qBh = &Bh_s[slot][0]; short* qBl = &Bl_s[slot][0];
        uint4 h, l;
        split2(av[0],  av[1],  h.x, l.x); split2(av[2],  av[3],  h.y, l.y);
        split2(av[4],  av[5],  h.z, l.z); split2(av[6],  av[7],  h.w, l.w);
        *(uint4*)&qAh[wo0] = h; *(uint4*)&qAl[wo0] = l;
        split2(av[8],  av[9],  h.x, l.x); split2(av[10], av[11], h.y, l.y);
        split2(av[12], av[13], h.z, l.z); split2(av[14], av[15], h.w, l.w);
        *(uint4*)&qAh[wo1] = h; *(uint4*)&qAl[wo1] = l;
        split2(bv[0],  bv[1],  h.x, l.x); split2(bv[2],  bv[3],  h.y, l.y);
        split2(bv[4],  bv[5],  h.z, l.z); split2(bv[6],  bv[7],  h.w, l.w);
        *(uint4*)&qBh[wo0] = h; *(uint4*)&qBl[wo0] = l;
        split2(bv[8],  bv[9],  h.x, l.x); split2(bv[10], bv[11], h.y, l.y);
        split2(bv[12], bv[13], h.z, l.z); split2(bv[14], bv[15], h.w, l.w);
        *(uint4*)&qBh[wo1] = h; *(uint4*)&qBl[wo1] = l;
    };

    // ---- prologue: stage tile 0 synchronously into slot 0 ----
    stage_load(0);
    stage_write(0);
    __syncthreads();

    for (int t = 0; t < 16; ++t) {
        const int s = t & 1;
        const short* pAh = &Ah_s[s][0]; const short* pAl = &Al_s[s][0];
        const short* pBh = &Bh_s[s][0]; const short* pBl = &Bl_s[s][0];

        // ---- issue next-tile global loads; consumed at tile END (full cover) ----
        if (t < 15) stage_load(t + 1);
        __builtin_amdgcn_sched_barrier(0);

        // ---- B fragments once per tile (8 b128) ----
        bf16x8 Bf_h[4], Bf_l[4];
#pragma unroll
        for (int ns = 0; ns < 4; ++ns) {
            const int o = (wc * 64 + ns * 16 + lm) * 32 + fpos8;
            Bf_h[ns] = *(const bf16x8*)&pBh[o];
            Bf_l[ns] = *(const bf16x8*)&pBl[o];
        }

        // ---- 4 phases: {read 2 A-frag pairs, 24 MFMA, barrier} ----
#pragma unroll
        for (int ph = 0; ph < 4; ++ph) {
            bf16x8 Af_h[2], Af_l[2];
#pragma unroll
            for (int u = 0; u < 2; ++u) {
                const int ms = ph * 2 + u;
                const int o = (wr * 128 + ms * 16 + lm) * 32 + fpos8;
                Af_h[u] = *(const bf16x8*)&pAh[o];
                Af_l[u] = *(const bf16x8*)&pAl[o];
            }
            __builtin_amdgcn_s_setprio(1);
#pragma unroll
            for (int u = 0; u < 2; ++u) {
                const int ms = ph * 2 + u;
#pragma unroll
                for (int ns = 0; ns < 4; ++ns) {
                    acc[ms][ns] = __builtin_amdgcn_mfma_f32_16x16x32_bf16(Af_h[u], Bf_h[ns], acc[ms][ns], 0, 0, 0);
                    acc[ms][ns] = __builtin_amdgcn_mfma_f32_16x16x32_bf16(Af_h[u], Bf_l[ns], acc[ms][ns], 0, 0, 0);
                    acc[ms][ns] = __builtin_amdgcn_mfma_f32_16x16x32_bf16(Af_l[u], Bf_h[ns], acc[ms][ns], 0, 0, 0);
                }
            }
            __builtin_amdgcn_s_setprio(0);
            if (ph < 3) __builtin_amdgcn_s_barrier();
        }

        // ---- split + write tile t+1 into the freed slot; then flip ----
        __builtin_amdgcn_sched_barrier(0);
        if (t < 15) stage_write(s ^ 1);
        __syncthreads();
    }

    // ---- write C: D layout col=lane&15, row=quad*4+reg (verified R5-R8) ----
#pragma unroll
    for (int ms = 0; ms < 8; ++ms) {
        const int rowb = m0 + wr * 128 + ms * 16 + quad * 4;
#pragma unroll
        for (int ns = 0; ns < 4; ++ns) {
            const int col = n0 + wc * 64 + ns * 16 + lm;
#pragma unroll
            for (int r = 0; r < 4; ++r)
                fW[((size_t)(rowb + r) * I_SZ + i) * N_SZ + col] = acc[ms][ns][r];
        }
    }
}

// ---------------------------------------------------------------------------
// Kernel 2: routing via Gram matrices (unchanged).
// ---------------------------------------------------------------------------
__global__ __launch_bounds__(1024) void routing_kernel(
    const float* __restrict__ fW,  // [B, I, N]
    const float* __restrict__ p,   // [B, I]
    float* __restrict__ c_out,     // [B, J, E]
    float* __restrict__ r_out)     // [B, I, J]
{
    const int b   = blockIdx.x;
    const int tid = threadIdx.x;
    const int j   = tid >> 4;      // 0..63
    const int sub = tid & 15;      // e-chunk [sub*8, sub*8+8)

    __shared__ float G_sh[64][49];
    __shared__ float s_sh[64][9];
    __shared__ float w_sh[2][64][9];
    __shared__ float p_sh[8];

    if (tid < I_SZ) p_sh[tid] = p[(size_t)b * I_SZ + tid];

    float4 fw[I_SZ][2];
    const float* base = fW + (size_t)b * I_SZ * N_SZ + j * E_SZ + sub * 8;
#pragma unroll
    for (int i = 0; i < I_SZ; ++i) {
        fw[i][0] = *(const float4*)(base + (size_t)i * N_SZ);
        fw[i][1] = *(const float4*)(base + (size_t)i * N_SZ + 4);
    }

    // ---- Phase 1: Gram + row sums (reduce over 16 sub-lanes) ----
#pragma unroll
    for (int i = 0; i < I_SZ; ++i) {
        float s = fw[i][0].x + fw[i][0].y + fw[i][0].z + fw[i][0].w
                + fw[i][1].x + fw[i][1].y + fw[i][1].z + fw[i][1].w;
        s += __shfl_xor(s, 1); s += __shfl_xor(s, 2);
        s += __shfl_xor(s, 4); s += __shfl_xor(s, 8);
        if (sub == 0) s_sh[j][i] = s;
#pragma unroll
        for (int i2 = i; i2 < I_SZ; ++i2) {
            float g = fw[i][0].x * fw[i2][0].x + fw[i][0].y * fw[i2][0].y
                    + fw[i][0].z * fw[i2][0].z + fw[i][0].w * fw[i2][0].w
                    + fw[i][1].x * fw[i2][1].x + fw[i][1].y * fw[i2][1].y
                    + fw[i][1].z * fw[i2][1].z + fw[i][1].w * fw[i2][1].w;
            g += __shfl_xor(g, 1); g += __shfl_xor(g, 2);
            g += __shfl_xor(g, 4); g += __shfl_xor(g, 8);
            if (sub == 0) { G_sh[j][i * 7 + i2] = g; G_sh[j][i2 * 7 + i] = g; }
        }
    }
    __syncthreads();

    // ---- Phase 2: 10 iterations on the 7x7 system ----
    for (int t = 0; t < ITERS; ++t) {
        if (tid < I_SZ * 64) {                 // waves 0..6
            const int ii = tid >> 6;
            const int jj = tid & 63;
            float l;
            if (t == 0) {
                l = s_sh[jj][ii];              // c0 = ones
            } else {
                const int rb = t & 1;
                l = 0.f;
#pragma unroll
                for (int i2 = 0; i2 < I_SZ; ++i2)
                    l = fmaf(w_sh[rb][jj][i2], G_sh[jj][ii * 7 + i2], l);
            }
            float mx = l;
#pragma unroll
            for (int off = 32; off > 0; off >>= 1)
                mx = fmaxf(mx, __shfl_xor(mx, off));
            float ex = __expf(l - mx);
            float sm = ex;
#pragma unroll
            for (int off = 32; off > 0; off >>= 1)
                sm += __shfl_xor(sm, off);
            float r = ex / sm;
            if (t == ITERS - 1)
                r_out[(size_t)b * (I_SZ * J_SZ) + ii * 64 + jj] = r;
            w_sh[(t + 1) & 1][jj][ii] = p_sh[ii] * r;
        }
        __syncthreads();
    }

    // ---- Phase 3: c from registers ----
    float4 a0 = make_float4(0.f, 0.f, 0.f, 0.f);
    float4 a1 = make_float4(0.f, 0.f, 0.f, 0.f);
#pragma unroll
    for (int i = 0; i < I_SZ; ++i) {
        float wv = w_sh[ITERS & 1][j][i];
        a0.x = fmaf(wv, fw[i][0].x, a0.x); a0.y = fmaf(wv, fw[i][0].y, a0.y);
        a0.z = fmaf(wv, fw[i][0].z, a0.z); a0.w = fmaf(wv, fw[i][0].w, a0.w);
        a1.x = fmaf(wv, fw[i][1].x, a1.x); a1.y = fmaf(wv, fw[i][1].y, a1.y);
        a1.z = fmaf(wv, fw[i][1].z, a1.z); a1.w = fmaf(wv, fw[i][1].w, a1.w);
    }
    float* dst = c_out + (size_t)b * N_SZ + j * E_SZ + sub * 8;
    *(float4*)(dst)     = a0;
    *(float4*)(dst + 4) = a1;
}

extern "C" void kernel_launch(void* const* d_in, const int* in_sizes, int n_in,
                              void* d_out, int out_size, void* d_ws, size_t ws_size,
                              hipStream_t stream) {
    const float* f = (const float*)d_in[0];   // [512,7,512]
    const float* p = (const float*)d_in[1];   // [512,7]
    const float* W = (const float*)d_in[2];   // [7,512,64,128]
    float* out = (float*)d_out;               // c (512*64*128) then r (512*7*64)
    float* fW  = (float*)d_ws;                // 117.4 MB scratch

    vote_gemm_mfma<<<dim3(N_SZ / 256, B_SZ / 256, I_SZ), 512, 0, stream>>>(f, W, fW);
    routing_kernel<<<B_SZ, 1024, 0, stream>>>(fW, p, out, out + (size_t)B_SZ * N_SZ);
}